// Round 10
// baseline (149.087 us; speedup 1.0000x reference)
//
#include <hip/hip_runtime.h>

typedef __attribute__((ext_vector_type(8))) short short8;
typedef __attribute__((ext_vector_type(4))) short s16x4;
typedef __attribute__((ext_vector_type(4))) float f32x4;

#define NHEADS 12
#define SEQLEN 2048
#define HEADD  64
#define DMODEL 768

// f32 -> bf16 round-to-nearest-even
__device__ __forceinline__ short cvtbf(float f) {
  unsigned u = __builtin_bit_cast(unsigned, f);
  u += 0x7fffu + ((u >> 16) & 1u);
  return (short)(u >> 16);
}
// bf16 -> f32
__device__ __forceinline__ float bf2f(short s) {
  unsigned u = ((unsigned)(unsigned short)s) << 16;
  return __builtin_bit_cast(float, u);
}

// async global->LDS, 16B per lane; lds base must be wave-uniform (HW adds lane*16)
__device__ __forceinline__ void gload16(const void* g, void* l) {
  __builtin_amdgcn_global_load_lds((const __attribute__((address_space(1))) void*)g,
                                   (__attribute__((address_space(3))) void*)l, 16, 0, 0);
}

// store high 16 bits of f32 (bf16 truncation) to LDS in ONE instruction, no VALU
__device__ __forceinline__ void ds_write_hi16(short* p, float v) {
  asm volatile("ds_write_b16_d16_hi %0, %1"
               : : "v"((__attribute__((address_space(3))) short*)p), "v"(v) : "memory");
}

// ---------------- kernel 1: fused prep (cast x + transpose weights) ----------------
// blocks [0,1536): cast x (4096x768 f32 -> bf16)
// blocks [1536,3840): transpose+cast the 4 weight matrices to [n][k] bf16
__global__ void prep_kernel(const float* __restrict__ x, short* __restrict__ xb,
                            const float* __restrict__ w0, const float* __restrict__ w1,
                            const float* __restrict__ w2, const float* __restrict__ w3,
                            short* __restrict__ wt, short* __restrict__ wot) {
  __shared__ float t[32][33];
  const int tid = threadIdx.x;
  if (blockIdx.x < 1536) {
    int i = blockIdx.x * 256 + tid;
    const float* p = x + (size_t)i * 8;
    short8 v;
#pragma unroll
    for (int j = 0; j < 8; ++j) v[j] = cvtbf(p[j]);
    *(short8*)(xb + (size_t)i * 8) = v;
    return;
  }
  int bx = blockIdx.x - 1536;             // 0..2303
  int bz = bx / 576, rem = bx - bz * 576; // 576 = 24*24 blocks per matrix
  int bxx = rem % 24, byy = rem / 24;
  const float* W = bz == 0 ? w0 : bz == 1 ? w1 : bz == 2 ? w2 : w3;
  short* O = bz < 3 ? wt + (size_t)bz * (768 * 768) : wot;
  int tx = tid & 31, ty = tid >> 5;
  int n0 = bxx * 32, k0 = byy * 32;
#pragma unroll
  for (int j = 0; j < 4; ++j)
    t[ty + j * 8][tx] = W[(k0 + ty + j * 8) * 768 + n0 + tx];
  __syncthreads();
#pragma unroll
  for (int j = 0; j < 4; ++j)
    O[(n0 + ty + j * 8) * 768 + k0 + tx] = cvtbf(t[tx][ty + j * 8]);
}

// ------- shared GEMM core: C[128 x 128] = A[128xK] * Bt[128xK]^T, K=768 -------
// 4 waves, each owning a 64x64 output tile (4x4 of 16x16x32 frags).
// DBUF=false: 2-barrier loop, 32KB LDS; cross-block TLP hides the vmcnt(0)
//   drain (m97 structure). Use when grid >> CU count.
// DBUF=true: single-barrier double-buffered, 64KB LDS; use only when
//   grid <= 1 block/CU (within-block overlap is all there is).
template <bool DBUF>
__device__ __forceinline__ void gemm_core128(const short* __restrict__ A,
                                             const short* __restrict__ Bt,
                                             short* sA, short* sB,
                                             int bm, int bn, f32x4 acc[4][4]) {
  const int tid = threadIdx.x;
  const int w = tid >> 6, lane = tid & 63;
  const int quad = lane >> 4, l16 = lane & 15;
  const int wm = (w & 1) * 64, wn = (w >> 1) * 64;

  int gA[4], gB[4], lbase[4];
#pragma unroll
  for (int j = 0; j < 4; ++j) {
    int slot = j * 256 + w * 64 + lane;     // 1024 16B chunks per 128x64 tile
    int r = slot >> 3, c = (slot & 7) ^ (r & 7);
    gA[j] = (bm * 128 + r) * 768 + c * 8;
    gB[j] = (bn * 128 + r) * 768 + c * 8;
    lbase[j] = (j * 256 + w * 64) * 8;
  }

  if (DBUF) {
    // prologue: tile 0 -> buffer 0
#pragma unroll
    for (int j = 0; j < 4; ++j) {
      gload16(A + gA[j], sA + lbase[j]);
      gload16(Bt + gB[j], sB + lbase[j]);
    }
    int pb = 0;
    for (int kt = 0; kt < 12; ++kt) {
      __syncthreads();   // drains this wave's loads into buf pb; all done reading pb^1
      if (kt + 1 < 12) {
        int o = (pb ^ 1) * 8192;
#pragma unroll
        for (int j = 0; j < 4; ++j) {
          gload16(A + gA[j] + (kt + 1) * 64, sA + o + lbase[j]);
          gload16(Bt + gB[j] + (kt + 1) * 64, sB + o + lbase[j]);
        }
      }
      const short* pa = sA + pb * 8192;
      const short* pbv = sB + pb * 8192;
#pragma unroll
      for (int ks = 0; ks < 2; ++ks) {
        int cp = (ks * 4 + quad) ^ (l16 & 7);
        short8 a[4], b[4];
#pragma unroll
        for (int mt = 0; mt < 4; ++mt)
          a[mt] = *(const short8*)(pa + (wm + mt * 16 + l16) * 64 + cp * 8);
#pragma unroll
        for (int nt = 0; nt < 4; ++nt)
          b[nt] = *(const short8*)(pbv + (wn + nt * 16 + l16) * 64 + cp * 8);
#pragma unroll
        for (int mt = 0; mt < 4; ++mt)
#pragma unroll
          for (int nt = 0; nt < 4; ++nt)
            acc[mt][nt] = __builtin_amdgcn_mfma_f32_16x16x32_bf16(a[mt], b[nt], acc[mt][nt], 0, 0, 0);
      }
      pb ^= 1;
    }
  } else {
    for (int kt = 0; kt < 12; ++kt) {
      __syncthreads();
#pragma unroll
      for (int j = 0; j < 4; ++j) {
        gload16(A + gA[j] + kt * 64, sA + lbase[j]);
        gload16(Bt + gB[j] + kt * 64, sB + lbase[j]);
      }
      __syncthreads();
#pragma unroll
      for (int ks = 0; ks < 2; ++ks) {
        int cp = (ks * 4 + quad) ^ (l16 & 7);
        short8 a[4], b[4];
#pragma unroll
        for (int mt = 0; mt < 4; ++mt)
          a[mt] = *(const short8*)(sA + (wm + mt * 16 + l16) * 64 + cp * 8);
#pragma unroll
        for (int nt = 0; nt < 4; ++nt)
          b[nt] = *(const short8*)(sB + (wn + nt * 16 + l16) * 64 + cp * 8);
#pragma unroll
        for (int mt = 0; mt < 4; ++mt)
#pragma unroll
          for (int nt = 0; nt < 4; ++nt)
            acc[mt][nt] = __builtin_amdgcn_mfma_f32_16x16x32_bf16(a[mt], b[nt], acc[mt][nt], 0, 0, 0);
      }
    }
  }
}

// ---------------- kernel 2: fused QKV projection ----------------
// Q is pre-scaled by 0.125*log2(e) so attention needs no per-score multiply.
// Epilogue: LDS-repack -> 8x ds_read_b128 + 8x global_store_dwordx4 per
// thread, full 64B lines for all three output layouts.
__global__ __launch_bounds__(256, 3) void qkv_gemm(
    const short* __restrict__ A, const short* __restrict__ Bt,
    const float* __restrict__ bq, const float* __restrict__ bk, const float* __restrict__ bv,
    short* __restrict__ oq, short* __restrict__ ok, short* __restrict__ ov) {
  __shared__ short sAB[2 * 128 * 64];   // K-loop: A|B staging; epilogue: C tile
  f32x4 acc[4][4];
  const f32x4 z4 = {0.f, 0.f, 0.f, 0.f};
#pragma unroll
  for (int mt = 0; mt < 4; ++mt)
#pragma unroll
    for (int nt = 0; nt < 4; ++nt) acc[mt][nt] = z4;

  const int bm = blockIdx.x, bn = blockIdx.y;
  gemm_core128<false>(A, Bt, sAB, sAB + 8192, bm, bn, acc);

  const int seg = bn / 6, bn_l = bn % 6;
  const float* bias = seg == 0 ? bq : seg == 1 ? bk : bv;
  short* outp = seg == 0 ? oq : seg == 1 ? ok : ov;

  const int tid = threadIdx.x;
  const int w = tid >> 6, lane = tid & 63;
  const int quad = lane >> 4, l16 = lane & 15;
  const int wm = (w & 1) * 64, wn = (w >> 1) * 64;

  __syncthreads();   // all waves done reading staging LDS; safe to repack

  // ---- write phase: acc -> swizzled 128x128 bf16 C tile ----
  if (seg < 2) {
    // rows = m, cols = n; chunk c = n>>3 swizzled by m&7
#pragma unroll
    for (int nt = 0; nt < 4; ++nt) {
      int n = wn + nt * 16 + l16;
      float bval = bias[bn_l * 128 + n];
      int c = n >> 3, nl = n & 7;
#pragma unroll
      for (int mt = 0; mt < 4; ++mt) {
#pragma unroll
        for (int r = 0; r < 4; ++r) {
          int m = wm + mt * 16 + quad * 4 + r;
          float v = acc[mt][nt][r] + bval;
          if (seg == 0) v *= 0.1803368801f;   // 0.125 * log2(e)
          sAB[m * 128 + ((c ^ (m & 7)) << 3) + nl] = cvtbf(v);
        }
      }
    }
  } else {
    // rows = n, cols = de-interleaved m: mm = (m&1)*64 + (m>>1) so the
    // s-dimension is contiguous per (b,h,d); chunk c = mm>>3 swizzled by n&7
#pragma unroll
    for (int nt = 0; nt < 4; ++nt) {
      int n = wn + nt * 16 + l16;
      float bval = bias[bn_l * 128 + n];
#pragma unroll
      for (int mt = 0; mt < 4; ++mt) {
#pragma unroll
        for (int r = 0; r < 4; ++r) {
          int m = wm + mt * 16 + quad * 4 + r;
          int mm = ((m & 1) << 6) | (m >> 1);
          float v = acc[mt][nt][r] + bval;
          sAB[n * 128 + (((mm >> 3) ^ (n & 7)) << 3) + (mm & 7)] = cvtbf(v);
        }
      }
    }
  }
  __syncthreads();

  // ---- read + store phase: 2048 16B chunks, 8 per thread, coalesced ----
  if (seg < 2) {
    // chunk ch -> (m = ch>>4, c = ch&15); out = Q/K [b][h][s][64]
#pragma unroll
    for (int j = 0; j < 8; ++j) {
      int ch = j * 256 + tid;
      int m = ch >> 4, c = ch & 15;
      short8 v = *(const short8*)(sAB + m * 128 + ((c ^ (m & 7)) << 3));
      int mg = bm * 128 + m;
      int s = mg >> 1, b = mg & 1;
      int h = bn_l * 2 + (c >> 3), d0 = (c & 7) * 8;
      *(short8*)(outp + (((size_t)(b * NHEADS + h) * SEQLEN + s) * HEADD + d0)) = v;
    }
  } else {
    // chunk ch -> (n = ch>>4, c = ch&15); c>>3 = b, (c&7)*8 = s_local
    // out = V^T [b][h][d][s], s contiguous
#pragma unroll
    for (int j = 0; j < 8; ++j) {
      int ch = j * 256 + tid;
      int n = ch >> 4, c = ch & 15;
      short8 v = *(const short8*)(sAB + n * 128 + ((c ^ (n & 7)) << 3));
      int b = c >> 3, s0 = bm * 64 + (c & 7) * 8;
      int h = bn_l * 2 + (n >> 6), d = n & 63;
      *(short8*)(outp + (((size_t)(b * NHEADS + h) * HEADD + d) * SEQLEN + s0)) = v;
    }
  }
}

// -------- attn work table: 80 entries {qi | ts<<8 | ntl<<16}, heavy-first --------
#define AE(qi, ts, nt) ((qi) | ((ts) << 8) | ((nt) << 16))
__device__ const int ATTN_TAB[80] = {
  AE(31,0,8), AE(31,8,8), AE(31,16,8), AE(31,24,8),
  AE(30,0,8), AE(30,8,8), AE(30,16,8),
  AE(29,0,8), AE(29,8,8), AE(29,16,8),
  AE(28,0,8), AE(28,8,8), AE(28,16,8),
  AE(27,0,8), AE(27,8,8), AE(27,16,8),
  AE(26,0,8), AE(26,8,8), AE(26,16,8),
  AE(25,0,8), AE(25,8,8), AE(25,16,8),
  AE(24,0,8), AE(24,8,8), AE(24,16,8),
  AE(23,0,8), AE(23,8,8), AE(23,16,8),
  AE(22,0,8), AE(22,8,8),
  AE(21,0,8), AE(21,8,8),
  AE(20,0,8), AE(20,8,8),
  AE(19,0,8), AE(19,8,8),
  AE(18,0,8), AE(18,8,8),
  AE(17,0,8), AE(17,8,8),
  AE(16,0,8), AE(16,8,8),
  AE(15,0,8), AE(15,8,8),
  AE(14,0,8), AE(13,0,8), AE(12,0,8), AE(11,0,8),
  AE(10,0,8), AE(9,0,8),  AE(8,0,8),  AE(7,0,8),
  AE(30,24,7), AE(22,16,7), AE(14,8,7), AE(6,0,7),
  AE(29,24,6), AE(21,16,6), AE(13,8,6), AE(5,0,6),
  AE(28,24,5), AE(20,16,5), AE(12,8,5), AE(4,0,5),
  AE(27,24,4), AE(19,16,4), AE(11,8,4), AE(3,0,4),
  AE(26,24,3), AE(18,16,3), AE(10,8,3), AE(2,0,3),
  AE(25,24,2), AE(17,16,2), AE(9,8,2),  AE(1,0,2),
  AE(24,24,1), AE(16,16,1), AE(8,8,1),  AE(0,0,1),
};
// partial-slot base per qi (qi>=8 only; 72 slots per bh)
__device__ const int PBASE[32] = {
  0,0,0,0,0,0,0,0,
  0,2,4,6,8,10,12,14,
  16,19,22,25,28,31,34,37,
  40,44,48,52,56,60,64,68};

// ---------------- kernel 3: split-K flash attention ----------------
// grid 1920 = 80 entries x 24 bh. qi<8: single chunk -> Y direct.
// qi>=8: chunks write unnormalized (O bf16, l f32) partials; merge combines 2-4.
// bf16 partials halve the split-K round-trip traffic (61 -> 33 MB); error
// contribution after /l normalization ~1e-4 << threshold.
// Double-buffered K/V (one barrier per tile); l computed via ones-MFMA.
// R8 lesson: do NOT fuse the merge — per-block device-scope threadfence on
// non-coherent per-XCD L2 = L2 writeback/invalidate storm (318us, 10x).
__global__ __launch_bounds__(256, 4) void attn_kernel(
    const short* __restrict__ Q, const short* __restrict__ K,
    const short* __restrict__ Vt, short* __restrict__ Y,
    short* __restrict__ Of, float* __restrict__ lf) {
  __shared__ short sK[2][64 * 64];   // [t][d], swizzled
  __shared__ short sV[2][64 * 64];   // [d][t], swizzled
  __shared__ short sP[64 * 64];      // [q][t], swizzled, wave-private rows
  const int tid = threadIdx.x;
  const int w = tid >> 6, lane = tid & 63;
  const int quad = lane >> 4, l16 = lane & 15;
  const int e = ATTN_TAB[blockIdx.x / 24];
  const int bh = blockIdx.x % 24;
  const int qi = e & 255, ts = (e >> 8) & 255, ntl = e >> 16;
  const int q0 = qi << 6;
  const short* Qb = Q + (size_t)bh * (SEQLEN * HEADD);
  const short* Kb = K + (size_t)bh * (SEQLEN * HEADD);
  const short* Vb = Vt + (size_t)bh * (SEQLEN * HEADD);  // [64][2048]

  // Q fragments in registers (A-operand: m=l16 row, k=quad*8+j); pre-scaled
  short8 aq[2];
#pragma unroll
  for (int ks = 0; ks < 2; ++ks)
    aq[ks] = *(const short8*)(Qb + (q0 + w * 16 + l16) * 64 + ks * 32 + quad * 8);

  const short8 bones = {0x3F80, 0x3F80, 0x3F80, 0x3F80, 0x3F80, 0x3F80, 0x3F80, 0x3F80};
  f32x4 acc_o[4], acc_l;
  const f32x4 z4 = {0.f, 0.f, 0.f, 0.f};
#pragma unroll
  for (int nt = 0; nt < 4; ++nt) acc_o[nt] = z4;
  acc_l = z4;

  int gK[2], gV[2], lbase[2];
#pragma unroll
  for (int j = 0; j < 2; ++j) {
    int slot = j * 256 + w * 64 + lane;       // 512 16B chunks per 64x64 tile
    int r = slot >> 3, c = (slot & 7) ^ (r & 7);
    gK[j] = r * 64 + c * 8;
    gV[j] = r * 2048 + c * 8;
    lbase[j] = (j * 256 + w * 64) * 8;
  }

  const int qrow = q0 + w * 16 + quad * 4;
  const int tend = ts + ntl;

  // prologue: issue first tile into buffer 0
#pragma unroll
  for (int j = 0; j < 2; ++j) {
    gload16(Kb + (ts << 6) * 64 + gK[j], &sK[0][lbase[j]]);
    gload16(Vb + (ts << 6) + gV[j], &sV[0][lbase[j]]);
  }

  int pb = 0;
  for (int it = ts; it < tend; ++it) {
    __syncthreads();    // drains this wave's loads into buf pb; all waves done reading buf pb^1
    if (it + 1 < tend) {
      const int t1 = (it + 1) << 6;
#pragma unroll
      for (int j = 0; j < 2; ++j) {
        gload16(Kb + t1 * 64 + gK[j], &sK[pb ^ 1][lbase[j]]);
        gload16(Vb + t1 + gV[j], &sV[pb ^ 1][lbase[j]]);
      }
    }
    const short* sk = sK[pb];
    const short* sv = sV[pb];

    // S = Q K^T  (4 n-tiles of 16 t-cols)
    f32x4 sc[4];
#pragma unroll
    for (int nt = 0; nt < 4; ++nt) sc[nt] = z4;
#pragma unroll
    for (int ks = 0; ks < 2; ++ks) {
      int cp = (ks * 4 + quad) ^ (l16 & 7);
#pragma unroll
      for (int nt = 0; nt < 4; ++nt) {
        short8 bk = *(const short8*)(sk + (nt * 16 + l16) * 64 + cp * 8);
        sc[nt] = __builtin_amdgcn_mfma_f32_16x16x32_bf16(aq[ks], bk, sc[nt], 0, 0, 0);
      }
    }

    // causal mask on the diagonal tile
    if (it == qi) {
      const int t0 = it << 6;
#pragma unroll
      for (int nt = 0; nt < 4; ++nt)
#pragma unroll
        for (int r = 0; r < 4; ++r) {
          int t = t0 + nt * 16 + l16;
          if (t > qrow + r) sc[nt][r] = -1e30f;
        }
    }

    // p = exp2(s); truncate-store to LDS with zero VALU (d16_hi)
#pragma unroll
    for (int nt = 0; nt < 4; ++nt)
#pragma unroll
      for (int r = 0; r < 4; ++r) {
        float p = __builtin_amdgcn_exp2f(sc[nt][r]);
        int rq = w * 16 + quad * 4 + r;
        int t = nt * 16 + l16;
        int c = t >> 3;
        ds_write_hi16(&sP[rq * 64 + ((c ^ (rq & 7)) * 8 + (t & 7))], p);
      }

    // O += P V ; l += P * ones (2 k-steps)
#pragma unroll
    for (int kst = 0; kst < 2; ++kst) {
      int rq = w * 16 + l16;
      int cpa = (kst * 4 + quad) ^ (rq & 7);
      short8 ap = *(const short8*)(sP + rq * 64 + cpa * 8);
      acc_l = __builtin_amdgcn_mfma_f32_16x16x32_bf16(ap, bones, acc_l, 0, 0, 0);
#pragma unroll
      for (int nt = 0; nt < 4; ++nt) {
        int row = nt * 16 + l16;
        int cv = (kst * 4 + quad) ^ (row & 7);
        short8 bv = *(const short8*)(sv + row * 64 + cv * 8);
        acc_o[nt] = __builtin_amdgcn_mfma_f32_16x16x32_bf16(ap, bv, acc_o[nt], 0, 0, 0);
      }
    }
    pb ^= 1;
  }

  if (qi < 8) {
    // single chunk: normalize + write Y[(s*2+b)][h*64+d] bf16
    const int b = bh / NHEADS, h = bh % NHEADS;
#pragma unroll
    for (int r = 0; r < 4; ++r) {
      float rl = __builtin_amdgcn_rcpf(acc_l[r]);
      int srow = q0 + w * 16 + quad * 4 + r;
#pragma unroll
      for (int nt = 0; nt < 4; ++nt)
        Y[(srow * 2 + b) * DMODEL + h * 64 + nt * 16 + l16] = cvtbf(acc_o[nt][r] * rl);
    }
  } else {
    // write unnormalized partial (O bf16, l f32)
    const int slot = bh * 72 + PBASE[qi] + (ts >> 3);
    short* Ob = Of + (size_t)slot * 4096;
#pragma unroll
    for (int r = 0; r < 4; ++r) {
      int row = w * 16 + quad * 4 + r;
#pragma unroll
      for (int nt = 0; nt < 4; ++nt)
        Ob[row * 64 + nt * 16 + l16] = cvtbf(acc_o[nt][r]);
      if (l16 == 0) lf[slot * 64 + row] = acc_l[r];
    }
  }
}

// ---------------- kernel 3b: merge 2-4 bf16 partials for qi>=8 ----------------
// grid 576 = 24 qi x 24 bh; 256 threads, 2x short8 groups each (f32 accumulate)
__global__ void attn_merge(const short* __restrict__ Of, const float* __restrict__ lf,
                           short* __restrict__ Y) {
  const int bh = blockIdx.x % 24, qi = 8 + blockIdx.x / 24;
  const int nch = (qi >> 3) + 1;             // 2,3,4
  const int base = bh * 72 + PBASE[qi];
  const short* O0 = Of + (size_t)base * 4096;
  const float* L0 = lf + base * 64;
  const int b = bh / NHEADS, h = bh % NHEADS;
  const int tid = threadIdx.x;
#pragma unroll
  for (int j = 0; j < 2; ++j) {
    int i8 = j * 256 + tid;                  // 8-elem group index, 512 per (qi,bh)
    int row = i8 >> 3, col8 = (i8 & 7) * 8;
    float o[8];
    {
      short8 v = *(const short8*)(O0 + (size_t)i8 * 8);
#pragma unroll
      for (int k = 0; k < 8; ++k) o[k] = bf2f(v[k]);
    }
    float l = L0[row];
    for (int c = 1; c < nch; ++c) {
      short8 v = *(const short8*)(O0 + (size_t)c * 4096 + (size_t)i8 * 8);
#pragma unroll
      for (int k = 0; k < 8; ++k) o[k] += bf2f(v[k]);
      l += L0[c * 64 + row];
    }
    float rl = __builtin_amdgcn_rcpf(l);
    short8 y;
#pragma unroll
    for (int k = 0; k < 8; ++k) y[k] = cvtbf(o[k] * rl);
    int srow = qi * 64 + row;
    *(short8*)(Y + (size_t)(srow * 2 + b) * DMODEL + h * 64 + col8) = y;
  }
}

// ---------------- kernel 4: output projection (f32 out + bias) ----------------
// 192 blocks (<1/CU) -> double-buffered K-loop to hide the load drain in-block.
// Epilogue: LDS-repack (the dead 64KB A|B double-buffer exactly fits the
// 128x128 f32 C tile, chunk-XOR swizzled) -> 16x ds_read_b128 +
// 16x global_store_dwordx4 per thread, 512B-contiguous row segments.
__global__ __launch_bounds__(256, 2) void oproj_gemm(
    const short* __restrict__ A, const short* __restrict__ Bt,
    const float* __restrict__ bo, float* __restrict__ out) {
  __shared__ __align__(16) short sAB[4 * 128 * 64];  // K-loop: A dbuf | B dbuf; epilogue: f32 C tile
  f32x4 acc[4][4];
  const f32x4 z4 = {0.f, 0.f, 0.f, 0.f};
#pragma unroll
  for (int mt = 0; mt < 4; ++mt)
#pragma unroll
    for (int nt = 0; nt < 4; ++nt) acc[mt][nt] = z4;

  const int bm = blockIdx.x, bn = blockIdx.y;
  gemm_core128<true>(A, Bt, sAB, sAB + 16384, bm, bn, acc);

  const int tid = threadIdx.x;
  const int w = tid >> 6, lane = tid & 63;
  const int quad = lane >> 4, l16 = lane & 15;
  const int wm = (w & 1) * 64, wn = (w >> 1) * 64;

  __syncthreads();   // all waves done with staging LDS; safe to repack
  float* ct = (float*)sAB;

  // ---- write phase: acc+bias -> swizzled 128x128 f32 C tile ----
#pragma unroll
  for (int nt = 0; nt < 4; ++nt) {
    int n = wn + nt * 16 + l16;
    float bval = bo[bn * 128 + n];
    int c = n >> 2, n3 = n & 3;
#pragma unroll
    for (int mt = 0; mt < 4; ++mt) {
#pragma unroll
      for (int r = 0; r < 4; ++r) {
        int m = wm + mt * 16 + quad * 4 + r;
        ct[m * 128 + ((c ^ (m & 7)) << 2) + n3] = acc[mt][nt][r] + bval;
      }
    }
  }
  __syncthreads();

  // ---- read + store phase: 4096 16B chunks, 16 per thread ----
#pragma unroll
  for (int j = 0; j < 16; ++j) {
    int ch = j * 256 + tid;
    int m = ch >> 5, c = ch & 31;
    f32x4 v = *(const f32x4*)(ct + m * 128 + ((c ^ (m & 7)) << 2));
    *(f32x4*)(out + (size_t)(bm * 128 + m) * 768 + bn * 128 + c * 4) = v;
  }
}

extern "C" void kernel_launch(void* const* d_in, const int* in_sizes, int n_in,
                              void* d_out, int out_size, void* d_ws, size_t ws_size,
                              hipStream_t stream) {
  const float* x  = (const float*)d_in[0];
  const float* Wq = (const float*)d_in[1];
  const float* bq = (const float*)d_in[2];
  const float* Wk = (const float*)d_in[3];
  const float* bk = (const float*)d_in[4];
  const float* Wv = (const float*)d_in[5];
  const float* bv = (const float*)d_in[6];
  const float* Wo = (const float*)d_in[7];
  const float* bo = (const float*)d_in[8];
  float* out = (float*)d_out;

  short* ws  = (short*)d_ws;
  short* xb  = ws;                    // 3145728 shorts: x bf16 [4096][768]
  short* wt  = ws + 3145728;          // 1769472: [2304][768] Wq^T,Wk^T,Wv^T
  short* wot = ws + 4915200;          //  589824: Wo^T [768][768]
  short* qw  = ws + 5505024;          // 3145728: Q (pre-scaled) [b][h][s][64]
  short* kw  = ws + 8650752;          // 3145728: K [b][h][s][64]
  short* vw  = ws + 11796480;         // 3145728: V^T [b][h][64][s]
  short* yw  = ws + 14942208;         // 3145728: attn out [4096][768]
  short* Ofs = ws + 18087936;         // 1728 slots x 4096 bf16 partial O (14.2 MB)
  float* lf  = (float*)(Ofs + 7077888); // 1728 slots x 64 f32 partial l

  prep_kernel<<<3840, 256, 0, stream>>>(x, xb, Wq, Wk, Wv, Wo, wt, wot);
  qkv_gemm<<<dim3(32, 18), 256, 0, stream>>>(xb, wt, bq, bk, bv, qw, kw, vw);
  attn_kernel<<<1920, 256, 0, stream>>>(qw, kw, vw, yw, Ofs, lf);
  attn_merge<<<576, 256, 0, stream>>>(Ofs, lf, yw);
  oproj_gemm<<<dim3(32, 6), 256, 0, stream>>>(yw, wot, bo, out);
}

// Round 11
// 146.119 us; speedup vs baseline: 1.0203x; 1.0203x over previous
//
#include <hip/hip_runtime.h>

typedef __attribute__((ext_vector_type(8))) short short8;
typedef __attribute__((ext_vector_type(4))) short s16x4;
typedef __attribute__((ext_vector_type(4))) float f32x4;

#define NHEADS 12
#define SEQLEN 2048
#define HEADD  64
#define DMODEL 768

// f32 -> bf16 round-to-nearest-even
__device__ __forceinline__ short cvtbf(float f) {
  unsigned u = __builtin_bit_cast(unsigned, f);
  u += 0x7fffu + ((u >> 16) & 1u);
  return (short)(u >> 16);
}

// async global->LDS, 16B per lane; lds base must be wave-uniform (HW adds lane*16)
__device__ __forceinline__ void gload16(const void* g, void* l) {
  __builtin_amdgcn_global_load_lds((const __attribute__((address_space(1))) void*)g,
                                   (__attribute__((address_space(3))) void*)l, 16, 0, 0);
}

// store high 16 bits of f32 (bf16 truncation) to LDS in ONE instruction, no VALU
__device__ __forceinline__ void ds_write_hi16(short* p, float v) {
  asm volatile("ds_write_b16_d16_hi %0, %1"
               : : "v"((__attribute__((address_space(3))) short*)p), "v"(v) : "memory");
}

// ---------------- kernel 1: fused prep (cast x + transpose weights) ----------------
// blocks [0,1536): cast x (4096x768 f32 -> bf16)
// blocks [1536,3840): transpose+cast the 4 weight matrices to [n][k] bf16
__global__ void prep_kernel(const float* __restrict__ x, short* __restrict__ xb,
                            const float* __restrict__ w0, const float* __restrict__ w1,
                            const float* __restrict__ w2, const float* __restrict__ w3,
                            short* __restrict__ wt, short* __restrict__ wot) {
  __shared__ float t[32][33];
  const int tid = threadIdx.x;
  if (blockIdx.x < 1536) {
    int i = blockIdx.x * 256 + tid;
    const float* p = x + (size_t)i * 8;
    short8 v;
#pragma unroll
    for (int j = 0; j < 8; ++j) v[j] = cvtbf(p[j]);
    *(short8*)(xb + (size_t)i * 8) = v;
    return;
  }
  int bx = blockIdx.x - 1536;             // 0..2303
  int bz = bx / 576, rem = bx - bz * 576; // 576 = 24*24 blocks per matrix
  int bxx = rem % 24, byy = rem / 24;
  const float* W = bz == 0 ? w0 : bz == 1 ? w1 : bz == 2 ? w2 : w3;
  short* O = bz < 3 ? wt + (size_t)bz * (768 * 768) : wot;
  int tx = tid & 31, ty = tid >> 5;
  int n0 = bxx * 32, k0 = byy * 32;
#pragma unroll
  for (int j = 0; j < 4; ++j)
    t[ty + j * 8][tx] = W[(k0 + ty + j * 8) * 768 + n0 + tx];
  __syncthreads();
#pragma unroll
  for (int j = 0; j < 4; ++j)
    O[(n0 + ty + j * 8) * 768 + k0 + tx] = cvtbf(t[tx][ty + j * 8]);
}

// ------- shared GEMM core: C[128 x 128] = A[128xK] * Bt[128xK]^T, K=768 -------
// 4 waves, each owning a 64x64 output tile (4x4 of 16x16x32 frags).
// DBUF=false: 2-barrier loop, 32KB LDS; cross-block TLP hides the vmcnt(0)
//   drain (m97 structure). Use when grid >> CU count.
// DBUF=true: single-barrier double-buffered, 64KB LDS; use only when
//   grid <= 1 block/CU (within-block overlap is all there is).
template <bool DBUF>
__device__ __forceinline__ void gemm_core128(const short* __restrict__ A,
                                             const short* __restrict__ Bt,
                                             short* sA, short* sB,
                                             int bm, int bn, f32x4 acc[4][4]) {
  const int tid = threadIdx.x;
  const int w = tid >> 6, lane = tid & 63;
  const int quad = lane >> 4, l16 = lane & 15;
  const int wm = (w & 1) * 64, wn = (w >> 1) * 64;

  int gA[4], gB[4], lbase[4];
#pragma unroll
  for (int j = 0; j < 4; ++j) {
    int slot = j * 256 + w * 64 + lane;     // 1024 16B chunks per 128x64 tile
    int r = slot >> 3, c = (slot & 7) ^ (r & 7);
    gA[j] = (bm * 128 + r) * 768 + c * 8;
    gB[j] = (bn * 128 + r) * 768 + c * 8;
    lbase[j] = (j * 256 + w * 64) * 8;
  }

  if (DBUF) {
    // prologue: tile 0 -> buffer 0
#pragma unroll
    for (int j = 0; j < 4; ++j) {
      gload16(A + gA[j], sA + lbase[j]);
      gload16(Bt + gB[j], sB + lbase[j]);
    }
    int pb = 0;
    for (int kt = 0; kt < 12; ++kt) {
      __syncthreads();   // drains this wave's loads into buf pb; all done reading pb^1
      if (kt + 1 < 12) {
        int o = (pb ^ 1) * 8192;
#pragma unroll
        for (int j = 0; j < 4; ++j) {
          gload16(A + gA[j] + (kt + 1) * 64, sA + o + lbase[j]);
          gload16(Bt + gB[j] + (kt + 1) * 64, sB + o + lbase[j]);
        }
      }
      const short* pa = sA + pb * 8192;
      const short* pbv = sB + pb * 8192;
#pragma unroll
      for (int ks = 0; ks < 2; ++ks) {
        int cp = (ks * 4 + quad) ^ (l16 & 7);
        short8 a[4], b[4];
#pragma unroll
        for (int mt = 0; mt < 4; ++mt)
          a[mt] = *(const short8*)(pa + (wm + mt * 16 + l16) * 64 + cp * 8);
#pragma unroll
        for (int nt = 0; nt < 4; ++nt)
          b[nt] = *(const short8*)(pbv + (wn + nt * 16 + l16) * 64 + cp * 8);
#pragma unroll
        for (int mt = 0; mt < 4; ++mt)
#pragma unroll
          for (int nt = 0; nt < 4; ++nt)
            acc[mt][nt] = __builtin_amdgcn_mfma_f32_16x16x32_bf16(a[mt], b[nt], acc[mt][nt], 0, 0, 0);
      }
      pb ^= 1;
    }
  } else {
    for (int kt = 0; kt < 12; ++kt) {
      __syncthreads();
#pragma unroll
      for (int j = 0; j < 4; ++j) {
        gload16(A + gA[j] + kt * 64, sA + lbase[j]);
        gload16(Bt + gB[j] + kt * 64, sB + lbase[j]);
      }
      __syncthreads();
#pragma unroll
      for (int ks = 0; ks < 2; ++ks) {
        int cp = (ks * 4 + quad) ^ (l16 & 7);
        short8 a[4], b[4];
#pragma unroll
        for (int mt = 0; mt < 4; ++mt)
          a[mt] = *(const short8*)(sA + (wm + mt * 16 + l16) * 64 + cp * 8);
#pragma unroll
        for (int nt = 0; nt < 4; ++nt)
          b[nt] = *(const short8*)(sB + (wn + nt * 16 + l16) * 64 + cp * 8);
#pragma unroll
        for (int mt = 0; mt < 4; ++mt)
#pragma unroll
          for (int nt = 0; nt < 4; ++nt)
            acc[mt][nt] = __builtin_amdgcn_mfma_f32_16x16x32_bf16(a[mt], b[nt], acc[mt][nt], 0, 0, 0);
      }
    }
  }
}

// ---------------- kernel 2: fused QKV projection ----------------
// Q is pre-scaled by 0.125*log2(e) so attention needs no per-score multiply.
// Epilogue: LDS-repack -> 8x ds_read_b128 + 8x global_store_dwordx4 per
// thread, full 64B lines for all three output layouts.
__global__ __launch_bounds__(256, 3) void qkv_gemm(
    const short* __restrict__ A, const short* __restrict__ Bt,
    const float* __restrict__ bq, const float* __restrict__ bk, const float* __restrict__ bv,
    short* __restrict__ oq, short* __restrict__ ok, short* __restrict__ ov) {
  __shared__ short sAB[2 * 128 * 64];   // K-loop: A|B staging; epilogue: C tile
  f32x4 acc[4][4];
  const f32x4 z4 = {0.f, 0.f, 0.f, 0.f};
#pragma unroll
  for (int mt = 0; mt < 4; ++mt)
#pragma unroll
    for (int nt = 0; nt < 4; ++nt) acc[mt][nt] = z4;

  const int bm = blockIdx.x, bn = blockIdx.y;
  gemm_core128<false>(A, Bt, sAB, sAB + 8192, bm, bn, acc);

  const int seg = bn / 6, bn_l = bn % 6;
  const float* bias = seg == 0 ? bq : seg == 1 ? bk : bv;
  short* outp = seg == 0 ? oq : seg == 1 ? ok : ov;

  const int tid = threadIdx.x;
  const int w = tid >> 6, lane = tid & 63;
  const int quad = lane >> 4, l16 = lane & 15;
  const int wm = (w & 1) * 64, wn = (w >> 1) * 64;

  __syncthreads();   // all waves done reading staging LDS; safe to repack

  // ---- write phase: acc -> swizzled 128x128 bf16 C tile ----
  if (seg < 2) {
    // rows = m, cols = n; chunk c = n>>3 swizzled by m&7
#pragma unroll
    for (int nt = 0; nt < 4; ++nt) {
      int n = wn + nt * 16 + l16;
      float bval = bias[bn_l * 128 + n];
      int c = n >> 3, nl = n & 7;
#pragma unroll
      for (int mt = 0; mt < 4; ++mt) {
#pragma unroll
        for (int r = 0; r < 4; ++r) {
          int m = wm + mt * 16 + quad * 4 + r;
          float v = acc[mt][nt][r] + bval;
          if (seg == 0) v *= 0.1803368801f;   // 0.125 * log2(e)
          sAB[m * 128 + ((c ^ (m & 7)) << 3) + nl] = cvtbf(v);
        }
      }
    }
  } else {
    // rows = n, cols = de-interleaved m: mm = (m&1)*64 + (m>>1) so the
    // s-dimension is contiguous per (b,h,d); chunk c = mm>>3 swizzled by n&7
#pragma unroll
    for (int nt = 0; nt < 4; ++nt) {
      int n = wn + nt * 16 + l16;
      float bval = bias[bn_l * 128 + n];
#pragma unroll
      for (int mt = 0; mt < 4; ++mt) {
#pragma unroll
        for (int r = 0; r < 4; ++r) {
          int m = wm + mt * 16 + quad * 4 + r;
          int mm = ((m & 1) << 6) | (m >> 1);
          float v = acc[mt][nt][r] + bval;
          sAB[n * 128 + (((mm >> 3) ^ (n & 7)) << 3) + (mm & 7)] = cvtbf(v);
        }
      }
    }
  }
  __syncthreads();

  // ---- read + store phase: 2048 16B chunks, 8 per thread, coalesced ----
  if (seg < 2) {
    // chunk ch -> (m = ch>>4, c = ch&15); out = Q/K [b][h][s][64]
#pragma unroll
    for (int j = 0; j < 8; ++j) {
      int ch = j * 256 + tid;
      int m = ch >> 4, c = ch & 15;
      short8 v = *(const short8*)(sAB + m * 128 + ((c ^ (m & 7)) << 3));
      int mg = bm * 128 + m;
      int s = mg >> 1, b = mg & 1;
      int h = bn_l * 2 + (c >> 3), d0 = (c & 7) * 8;
      *(short8*)(outp + (((size_t)(b * NHEADS + h) * SEQLEN + s) * HEADD + d0)) = v;
    }
  } else {
    // chunk ch -> (n = ch>>4, c = ch&15); c>>3 = b, (c&7)*8 = s_local
    // out = V^T [b][h][d][s], s contiguous
#pragma unroll
    for (int j = 0; j < 8; ++j) {
      int ch = j * 256 + tid;
      int n = ch >> 4, c = ch & 15;
      short8 v = *(const short8*)(sAB + n * 128 + ((c ^ (n & 7)) << 3));
      int b = c >> 3, s0 = bm * 64 + (c & 7) * 8;
      int h = bn_l * 2 + (n >> 6), d = n & 63;
      *(short8*)(outp + (((size_t)(b * NHEADS + h) * HEADD + d) * SEQLEN + s0)) = v;
    }
  }
}

// -------- attn work table: 80 entries {qi | ts<<8 | ntl<<16}, heavy-first --------
#define AE(qi, ts, nt) ((qi) | ((ts) << 8) | ((nt) << 16))
__device__ const int ATTN_TAB[80] = {
  AE(31,0,8), AE(31,8,8), AE(31,16,8), AE(31,24,8),
  AE(30,0,8), AE(30,8,8), AE(30,16,8),
  AE(29,0,8), AE(29,8,8), AE(29,16,8),
  AE(28,0,8), AE(28,8,8), AE(28,16,8),
  AE(27,0,8), AE(27,8,8), AE(27,16,8),
  AE(26,0,8), AE(26,8,8), AE(26,16,8),
  AE(25,0,8), AE(25,8,8), AE(25,16,8),
  AE(24,0,8), AE(24,8,8), AE(24,16,8),
  AE(23,0,8), AE(23,8,8), AE(23,16,8),
  AE(22,0,8), AE(22,8,8),
  AE(21,0,8), AE(21,8,8),
  AE(20,0,8), AE(20,8,8),
  AE(19,0,8), AE(19,8,8),
  AE(18,0,8), AE(18,8,8),
  AE(17,0,8), AE(17,8,8),
  AE(16,0,8), AE(16,8,8),
  AE(15,0,8), AE(15,8,8),
  AE(14,0,8), AE(13,0,8), AE(12,0,8), AE(11,0,8),
  AE(10,0,8), AE(9,0,8),  AE(8,0,8),  AE(7,0,8),
  AE(30,24,7), AE(22,16,7), AE(14,8,7), AE(6,0,7),
  AE(29,24,6), AE(21,16,6), AE(13,8,6), AE(5,0,6),
  AE(28,24,5), AE(20,16,5), AE(12,8,5), AE(4,0,5),
  AE(27,24,4), AE(19,16,4), AE(11,8,4), AE(3,0,4),
  AE(26,24,3), AE(18,16,3), AE(10,8,3), AE(2,0,3),
  AE(25,24,2), AE(17,16,2), AE(9,8,2),  AE(1,0,2),
  AE(24,24,1), AE(16,16,1), AE(8,8,1),  AE(0,0,1),
};
// partial-slot base per qi (qi>=8 only; 72 slots per bh)
__device__ const int PBASE[32] = {
  0,0,0,0,0,0,0,0,
  0,2,4,6,8,10,12,14,
  16,19,22,25,28,31,34,37,
  40,44,48,52,56,60,64,68};

// ---------------- kernel 3: split-K flash attention ----------------
// grid 1920 = 80 entries x 24 bh. qi<8: single chunk -> Y direct.
// qi>=8: chunks write unnormalized (O,l) f32 partials; merge combines 2-4.
// Double-buffered K/V (one barrier per tile); l computed via ones-MFMA.
// R8 lesson: do NOT fuse the merge — per-block device-scope threadfence on
// non-coherent per-XCD L2 = L2 writeback/invalidate storm (318us, 10x).
// R10 lesson: bf16 partials are null (traffic is L3-absorbed; extra cvt costs).
__global__ __launch_bounds__(256, 4) void attn_kernel(
    const short* __restrict__ Q, const short* __restrict__ K,
    const short* __restrict__ Vt, short* __restrict__ Y,
    float* __restrict__ Of, float* __restrict__ lf) {
  __shared__ short sK[2][64 * 64];   // [t][d], swizzled
  __shared__ short sV[2][64 * 64];   // [d][t], swizzled
  __shared__ short sP[64 * 64];      // [q][t], swizzled, wave-private rows
  const int tid = threadIdx.x;
  const int w = tid >> 6, lane = tid & 63;
  const int quad = lane >> 4, l16 = lane & 15;
  const int e = ATTN_TAB[blockIdx.x / 24];
  const int bh = blockIdx.x % 24;
  const int qi = e & 255, ts = (e >> 8) & 255, ntl = e >> 16;
  const int q0 = qi << 6;
  const short* Qb = Q + (size_t)bh * (SEQLEN * HEADD);
  const short* Kb = K + (size_t)bh * (SEQLEN * HEADD);
  const short* Vb = Vt + (size_t)bh * (SEQLEN * HEADD);  // [64][2048]

  // Q fragments in registers (A-operand: m=l16 row, k=quad*8+j); pre-scaled
  short8 aq[2];
#pragma unroll
  for (int ks = 0; ks < 2; ++ks)
    aq[ks] = *(const short8*)(Qb + (q0 + w * 16 + l16) * 64 + ks * 32 + quad * 8);

  const short8 bones = {0x3F80, 0x3F80, 0x3F80, 0x3F80, 0x3F80, 0x3F80, 0x3F80, 0x3F80};
  f32x4 acc_o[4], acc_l;
  const f32x4 z4 = {0.f, 0.f, 0.f, 0.f};
#pragma unroll
  for (int nt = 0; nt < 4; ++nt) acc_o[nt] = z4;
  acc_l = z4;

  int gK[2], gV[2], lbase[2];
#pragma unroll
  for (int j = 0; j < 2; ++j) {
    int slot = j * 256 + w * 64 + lane;       // 512 16B chunks per 64x64 tile
    int r = slot >> 3, c = (slot & 7) ^ (r & 7);
    gK[j] = r * 64 + c * 8;
    gV[j] = r * 2048 + c * 8;
    lbase[j] = (j * 256 + w * 64) * 8;
  }

  const int qrow = q0 + w * 16 + quad * 4;
  const int tend = ts + ntl;

  // prologue: issue first tile into buffer 0
#pragma unroll
  for (int j = 0; j < 2; ++j) {
    gload16(Kb + (ts << 6) * 64 + gK[j], &sK[0][lbase[j]]);
    gload16(Vb + (ts << 6) + gV[j], &sV[0][lbase[j]]);
  }

  int pb = 0;
  for (int it = ts; it < tend; ++it) {
    __syncthreads();    // drains this wave's loads into buf pb; all waves done reading buf pb^1
    if (it + 1 < tend) {
      const int t1 = (it + 1) << 6;
#pragma unroll
      for (int j = 0; j < 2; ++j) {
        gload16(Kb + t1 * 64 + gK[j], &sK[pb ^ 1][lbase[j]]);
        gload16(Vb + t1 + gV[j], &sV[pb ^ 1][lbase[j]]);
      }
    }
    const short* sk = sK[pb];
    const short* sv = sV[pb];

    // S = Q K^T  (4 n-tiles of 16 t-cols)
    f32x4 sc[4];
#pragma unroll
    for (int nt = 0; nt < 4; ++nt) sc[nt] = z4;
#pragma unroll
    for (int ks = 0; ks < 2; ++ks) {
      int cp = (ks * 4 + quad) ^ (l16 & 7);
#pragma unroll
      for (int nt = 0; nt < 4; ++nt) {
        short8 bk = *(const short8*)(sk + (nt * 16 + l16) * 64 + cp * 8);
        sc[nt] = __builtin_amdgcn_mfma_f32_16x16x32_bf16(aq[ks], bk, sc[nt], 0, 0, 0);
      }
    }

    // causal mask on the diagonal tile
    if (it == qi) {
      const int t0 = it << 6;
#pragma unroll
      for (int nt = 0; nt < 4; ++nt)
#pragma unroll
        for (int r = 0; r < 4; ++r) {
          int t = t0 + nt * 16 + l16;
          if (t > qrow + r) sc[nt][r] = -1e30f;
        }
    }

    // p = exp2(s); truncate-store to LDS with zero VALU (d16_hi)
#pragma unroll
    for (int nt = 0; nt < 4; ++nt)
#pragma unroll
      for (int r = 0; r < 4; ++r) {
        float p = __builtin_amdgcn_exp2f(sc[nt][r]);
        int rq = w * 16 + quad * 4 + r;
        int t = nt * 16 + l16;
        int c = t >> 3;
        ds_write_hi16(&sP[rq * 64 + ((c ^ (rq & 7)) * 8 + (t & 7))], p);
      }

    // O += P V ; l += P * ones (2 k-steps)
#pragma unroll
    for (int kst = 0; kst < 2; ++kst) {
      int rq = w * 16 + l16;
      int cpa = (kst * 4 + quad) ^ (rq & 7);
      short8 ap = *(const short8*)(sP + rq * 64 + cpa * 8);
      acc_l = __builtin_amdgcn_mfma_f32_16x16x32_bf16(ap, bones, acc_l, 0, 0, 0);
#pragma unroll
      for (int nt = 0; nt < 4; ++nt) {
        int row = nt * 16 + l16;
        int cv = (kst * 4 + quad) ^ (row & 7);
        short8 bv = *(const short8*)(sv + row * 64 + cv * 8);
        acc_o[nt] = __builtin_amdgcn_mfma_f32_16x16x32_bf16(ap, bv, acc_o[nt], 0, 0, 0);
      }
    }
    pb ^= 1;
  }

  if (qi < 8) {
    // single chunk: normalize + write Y[(s*2+b)][h*64+d] bf16
    const int b = bh / NHEADS, h = bh % NHEADS;
#pragma unroll
    for (int r = 0; r < 4; ++r) {
      float rl = __builtin_amdgcn_rcpf(acc_l[r]);
      int srow = q0 + w * 16 + quad * 4 + r;
#pragma unroll
      for (int nt = 0; nt < 4; ++nt)
        Y[(srow * 2 + b) * DMODEL + h * 64 + nt * 16 + l16] = cvtbf(acc_o[nt][r] * rl);
    }
  } else {
    // write unnormalized partial (O, l) f32
    const int slot = bh * 72 + PBASE[qi] + (ts >> 3);
    float* Ob = Of + (size_t)slot * 4096;
#pragma unroll
    for (int r = 0; r < 4; ++r) {
      int row = w * 16 + quad * 4 + r;
#pragma unroll
      for (int nt = 0; nt < 4; ++nt)
        Ob[row * 64 + nt * 16 + l16] = acc_o[nt][r];
      if (l16 == 0) lf[slot * 64 + row] = acc_l[r];
    }
  }
}

// ---------------- kernel 3b: merge 2-4 partials for qi>=8 ----------------
// grid 576 = 24 qi x 24 bh; 256 threads, 4 float4 each
__global__ void attn_merge(const float* __restrict__ Of, const float* __restrict__ lf,
                           short* __restrict__ Y) {
  const int bh = blockIdx.x % 24, qi = 8 + blockIdx.x / 24;
  const int nch = (qi >> 3) + 1;             // 2,3,4
  const int base = bh * 72 + PBASE[qi];
  const float* O0 = Of + (size_t)base * 4096;
  const float* L0 = lf + base * 64;
  const int b = bh / NHEADS, h = bh % NHEADS;
  const int tid = threadIdx.x;
#pragma unroll
  for (int j = 0; j < 4; ++j) {
    int i4 = j * 256 + tid;                  // float4 index, 1024 per (qi,bh)
    int row = i4 >> 4, col4 = (i4 & 15) * 4;
    f32x4 o = *(const f32x4*)(O0 + (size_t)i4 * 4);
    float l = L0[row];
    for (int c = 1; c < nch; ++c) {
      o += *(const f32x4*)(O0 + (size_t)c * 4096 + (size_t)i4 * 4);
      l += L0[c * 64 + row];
    }
    float rl = __builtin_amdgcn_rcpf(l);
    s16x4 y;
#pragma unroll
    for (int k = 0; k < 4; ++k) y[k] = cvtbf(o[k] * rl);
    int srow = qi * 64 + row;
    *(s16x4*)(Y + (size_t)(srow * 2 + b) * DMODEL + h * 64 + col4) = y;
  }
}

// ---------------- kernel 4: output projection (f32 out + bias) ----------------
// 192 blocks (<1/CU) -> double-buffered K-loop to hide the load drain in-block.
// Epilogue: LDS-repack (the dead 64KB A|B double-buffer exactly fits the
// 128x128 f32 C tile, chunk-XOR swizzled) -> 16x ds_read_b128 +
// 16x global_store_dwordx4 per thread, 512B-contiguous row segments.
__global__ __launch_bounds__(256, 2) void oproj_gemm(
    const short* __restrict__ A, const short* __restrict__ Bt,
    const float* __restrict__ bo, float* __restrict__ out) {
  __shared__ __align__(16) short sAB[4 * 128 * 64];  // K-loop: A dbuf | B dbuf; epilogue: f32 C tile
  f32x4 acc[4][4];
  const f32x4 z4 = {0.f, 0.f, 0.f, 0.f};
#pragma unroll
  for (int mt = 0; mt < 4; ++mt)
#pragma unroll
    for (int nt = 0; nt < 4; ++nt) acc[mt][nt] = z4;

  const int bm = blockIdx.x, bn = blockIdx.y;
  gemm_core128<true>(A, Bt, sAB, sAB + 16384, bm, bn, acc);

  const int tid = threadIdx.x;
  const int w = tid >> 6, lane = tid & 63;
  const int quad = lane >> 4, l16 = lane & 15;
  const int wm = (w & 1) * 64, wn = (w >> 1) * 64;

  __syncthreads();   // all waves done with staging LDS; safe to repack
  float* ct = (float*)sAB;

  // ---- write phase: acc+bias -> swizzled 128x128 f32 C tile ----
#pragma unroll
  for (int nt = 0; nt < 4; ++nt) {
    int n = wn + nt * 16 + l16;
    float bval = bo[bn * 128 + n];
    int c = n >> 2, n3 = n & 3;
#pragma unroll
    for (int mt = 0; mt < 4; ++mt) {
#pragma unroll
      for (int r = 0; r < 4; ++r) {
        int m = wm + mt * 16 + quad * 4 + r;
        ct[m * 128 + ((c ^ (m & 7)) << 2) + n3] = acc[mt][nt][r] + bval;
      }
    }
  }
  __syncthreads();

  // ---- read + store phase: 4096 16B chunks, 16 per thread ----
#pragma unroll
  for (int j = 0; j < 16; ++j) {
    int ch = j * 256 + tid;
    int m = ch >> 5, c = ch & 31;
    f32x4 v = *(const f32x4*)(ct + m * 128 + ((c ^ (m & 7)) << 2));
    *(f32x4*)(out + (size_t)(bm * 128 + m) * 768 + bn * 128 + c * 4) = v;
  }
}

extern "C" void kernel_launch(void* const* d_in, const int* in_sizes, int n_in,
                              void* d_out, int out_size, void* d_ws, size_t ws_size,
                              hipStream_t stream) {
  const float* x  = (const float*)d_in[0];
  const float* Wq = (const float*)d_in[1];
  const float* bq = (const float*)d_in[2];
  const float* Wk = (const float*)d_in[3];
  const float* bk = (const float*)d_in[4];
  const float* Wv = (const float*)d_in[5];
  const float* bv = (const float*)d_in[6];
  const float* Wo = (const float*)d_in[7];
  const float* bo = (const float*)d_in[8];
  float* out = (float*)d_out;

  short* ws  = (short*)d_ws;
  short* xb  = ws;                    // 3145728 shorts: x bf16 [4096][768]
  short* wt  = ws + 3145728;          // 1769472: [2304][768] Wq^T,Wk^T,Wv^T
  short* wot = ws + 4915200;          //  589824: Wo^T [768][768]
  short* qw  = ws + 5505024;          // 3145728: Q (pre-scaled) [b][h][s][64]
  short* kw  = ws + 8650752;          // 3145728: K [b][h][s][64]
  short* vw  = ws + 11796480;         // 3145728: V^T [b][h][64][s]
  short* yw  = ws + 14942208;         // 3145728: attn out [4096][768]
  float* Of  = (float*)(ws + 18087936); // 1728 slots x 4096 f32 partial O (28.3 MB)
  float* lf  = Of + 7077888;            // 1728 slots x 64 f32 partial l

  prep_kernel<<<3840, 256, 0, stream>>>(x, xb, Wq, Wk, Wv, Wo, wt, wot);
  qkv_gemm<<<dim3(32, 18), 256, 0, stream>>>(xb, wt, bq, bk, bv, qw, kw, vw);
  attn_kernel<<<1920, 256, 0, stream>>>(qw, kw, vw, yw, Of, lf);
  attn_merge<<<576, 256, 0, stream>>>(Of, lf, yw);
  oproj_gemm<<<dim3(32, 6), 256, 0, stream>>>(yw, wot, bo, out);
}